// Round 9
// baseline (376.264 us; speedup 1.0000x reference)
//
#include <hip/hip_runtime.h>

#define F0 128
#define F1 64
#define F2 32

__device__ __forceinline__ int rfl(int v) { return __builtin_amdgcn_readfirstlane(v); }

// bf16 helpers (RNE)
__device__ __forceinline__ unsigned short f2b(float f) {
    unsigned u = __float_as_uint(f);
    return (unsigned short)((u + 0x7fffu + ((u >> 16) & 1u)) >> 16);
}
__device__ __forceinline__ float b2f(unsigned short u) {
    return __uint_as_float(((unsigned)u) << 16);
}

// ---------------- degree ----------------
__global__ void deg_count(const int* __restrict__ dst, int* __restrict__ deg, int E) {
    int e = blockIdx.x * blockDim.x + threadIdx.x;
    if (e < E) atomicAdd(&deg[dst[e]], 1);
}

// ---------------- fused scan: one block, 1024 threads; also writes dinv & cursor ----
__global__ __launch_bounds__(1024) void scan_all(const int* __restrict__ deg,
                                                 float* __restrict__ dinv,
                                                 int* __restrict__ rowptr,
                                                 int* __restrict__ cursor, int N) {
    const int T = 1024;
    int tid = threadIdx.x;
    int C = (N + T - 1) / T;
    int lo = tid * C, hi = lo + C; if (hi > N) hi = N;
    int sum = 0;
    for (int i = lo; i < hi; ++i) sum += deg[i];

    __shared__ int wsum[16];
    int lane = tid & 63, w = tid >> 6;
    int incl = sum;
    for (int o = 1; o < 64; o <<= 1) {
        int v = __shfl_up(incl, o, 64);
        if (lane >= o) incl += v;
    }
    if (lane == 63) wsum[w] = incl;
    __syncthreads();
    if (w == 0) {
        int v = (lane < 16) ? wsum[lane] : 0;
        int inc2 = v;
        for (int o = 1; o < 16; o <<= 1) {
            int u = __shfl_up(inc2, o, 64);
            if (lane >= o) inc2 += u;
        }
        if (lane < 16) wsum[lane] = inc2 - v;   // exclusive wave offsets
    }
    __syncthreads();
    int run = wsum[w] + (incl - sum);           // exclusive prefix for this thread
    for (int i = lo; i < hi; ++i) {
        int dv = deg[i];
        rowptr[i] = run;
        cursor[i] = run;
        dinv[i] = rsqrtf((float)(dv + 1));      // +1 self-loop
        run += dv;
    }
}

// ---------------- bucket, XCD-pinned by dst partition (blockIdx&7) ----------------
// Each node-range partition's csr region is written by only one XCD -> csr lines
// fill in-cache and write back once (round-8 post-mortem: 52 MB WRITE for 3.2 MB csr).
__global__ __launch_bounds__(256) void bucket8(const int* __restrict__ src,
                                               const int* __restrict__ dst,
                                               int* __restrict__ cursor,
                                               int* __restrict__ csr, int E, int N) {
    int part = blockIdx.x & 7;
    int g = blockIdx.x >> 3;
    int G = gridDim.x >> 3;
    int plo = (int)(((long long)N * part) >> 3);
    int phi = (int)(((long long)N * (part + 1)) >> 3);
    for (int e = g * 256 + threadIdx.x; e < E; e += G * 256) {
        int d = dst[e];
        if (d >= plo && d < phi) {
            int pos = atomicAdd(&cursor[d], 1);
            csr[pos] = src[e];
        }
    }
}

// ---------------- GEMM1: xws1b = bf16((x @ W1) * dinv[row])   [N,128]x[128,64] -------
// k-loop bound `kb` is a RUNTIME arg so the compiler cannot fully unroll
// (round-5 post-mortem: full unroll -> 256 VGPR -> 750 MB scratch spill).
__global__ __launch_bounds__(256) void gemm1(const float* __restrict__ x,
                                             const float* __restrict__ W1,
                                             const float* __restrict__ dinv,
                                             unsigned short* __restrict__ xws1b,
                                             int N, int kb) {
    __shared__ float sx[64][132];
    __shared__ float sW[64][64];
    int tid = threadIdx.x;
    int row0 = blockIdx.x * 64;

    for (int i = tid; i < 2048; i += 256) {
        int r = i >> 5, kq = i & 31;
        int gr = row0 + r;
        float4 v = make_float4(0.f, 0.f, 0.f, 0.f);
        if (gr < N) v = ((const float4*)(x + (size_t)gr * F0))[kq];
        *(float4*)(&sx[r][kq << 2]) = v;
    }

    int tx = tid & 15, ty = tid >> 4;
    int c0 = tx * 4, r0 = ty * 4;
    float acc[4][4] = {};

    const float4* W4 = (const float4*)W1;
    float4* sW4 = (float4*)(&sW[0][0]);

    for (int p = 0; p < 2; ++p) {
        if (p) __syncthreads();
        for (int i = tid; i < 1024; i += 256) sW4[i] = W4[p * 1024 + i];
        __syncthreads();
        int kbase = p * 64;
        for (int k = 0; k < kb; k += 4) {
            float a[4][4], b[4][4];
            #pragma unroll
            for (int rr = 0; rr < 4; ++rr)
                *(float4*)&a[rr][0] = *(const float4*)&sx[r0 + rr][kbase + k];
            #pragma unroll
            for (int j = 0; j < 4; ++j)
                *(float4*)&b[j][0] = *(const float4*)&sW[k + j][c0];
            #pragma unroll
            for (int j = 0; j < 4; ++j)
                #pragma unroll
                for (int rr = 0; rr < 4; ++rr)
                    #pragma unroll
                    for (int cc = 0; cc < 4; ++cc)
                        acc[rr][cc] += a[rr][j] * b[j][cc];
        }
    }

    #pragma unroll
    for (int rr = 0; rr < 4; ++rr) {
        int gr = row0 + r0 + rr;
        if (gr < N) {
            float s = dinv[gr];
            ushort4 o;
            o.x = f2b(acc[rr][0] * s); o.y = f2b(acc[rr][1] * s);
            o.z = f2b(acc[rr][2] * s); o.w = f2b(acc[rr][3] * s);
            *(ushort4*)&xws1b[gr * F1 + c0] = o;
        }
    }
}

// ---------------- gather1: h1 = relu(dinv[d]*(sum_in xws1[s] + xws1[d]) + b1) --------
__global__ __launch_bounds__(256) void gather1(const int* __restrict__ csr,
                                               const int* __restrict__ rowptr,
                                               const int* __restrict__ deg,
                                               const float* __restrict__ dinv,
                                               const unsigned short* __restrict__ xb,
                                               const float* __restrict__ b1,
                                               float* __restrict__ h1, int N) {
    int wid = (blockIdx.x * 256 + threadIdx.x) >> 6;
    int lane = threadIdx.x & 63;
    if (wid >= N) return;
    int node = rfl(wid);
    int start = rfl(rowptr[node]);
    int cnt = rfl(deg[node]);
    float a0 = 0.f, a1 = 0.f, a2 = 0.f, a3 = 0.f;
    float a4 = 0.f, a5 = 0.f, a6 = 0.f, a7 = 0.f;
    int j = 0;
    for (; j + 8 <= cnt; j += 8) {
        int s0 = rfl(csr[start + j]);
        int s1 = rfl(csr[start + j + 1]);
        int s2 = rfl(csr[start + j + 2]);
        int s3 = rfl(csr[start + j + 3]);
        int s4 = rfl(csr[start + j + 4]);
        int s5 = rfl(csr[start + j + 5]);
        int s6 = rfl(csr[start + j + 6]);
        int s7 = rfl(csr[start + j + 7]);
        a0 += b2f(xb[s0 * F1 + lane]);
        a1 += b2f(xb[s1 * F1 + lane]);
        a2 += b2f(xb[s2 * F1 + lane]);
        a3 += b2f(xb[s3 * F1 + lane]);
        a4 += b2f(xb[s4 * F1 + lane]);
        a5 += b2f(xb[s5 * F1 + lane]);
        a6 += b2f(xb[s6 * F1 + lane]);
        a7 += b2f(xb[s7 * F1 + lane]);
    }
    for (; j + 4 <= cnt; j += 4) {
        int s0 = rfl(csr[start + j]);
        int s1 = rfl(csr[start + j + 1]);
        int s2 = rfl(csr[start + j + 2]);
        int s3 = rfl(csr[start + j + 3]);
        a0 += b2f(xb[s0 * F1 + lane]);
        a1 += b2f(xb[s1 * F1 + lane]);
        a2 += b2f(xb[s2 * F1 + lane]);
        a3 += b2f(xb[s3 * F1 + lane]);
    }
    for (; j < cnt; ++j) {
        int s = rfl(csr[start + j]);
        a0 += b2f(xb[s * F1 + lane]);
    }
    float acc = ((a0 + a1) + (a2 + a3)) + ((a4 + a5) + (a6 + a7));
    float dd = dinv[node];
    float v = dd * (acc + b2f(xb[node * F1 + lane])) + b1[lane];
    h1[(size_t)node * F1 + lane] = fmaxf(v, 0.f);
}

// ---------------- GEMM2: xws2b = bf16((h1 @ W2) * dinv[row])   [N,64]x[64,32] --------
__global__ __launch_bounds__(256) void gemm2(const float* __restrict__ h1,
                                             const float* __restrict__ W2,
                                             const float* __restrict__ dinv,
                                             unsigned short* __restrict__ xws2b,
                                             int N, int kb) {
    __shared__ float sx[128][68];
    __shared__ float sW[64][32];
    int tid = threadIdx.x;
    int row0 = blockIdx.x * 128;

    for (int i = tid; i < 512; i += 256) ((float4*)&sW[0][0])[i] = ((const float4*)W2)[i];
    for (int i = tid; i < 2048; i += 256) {
        int r = i >> 4, kq = i & 15;
        int gr = row0 + r;
        float4 v = make_float4(0.f, 0.f, 0.f, 0.f);
        if (gr < N) v = ((const float4*)(h1 + (size_t)gr * F1))[kq];
        *(float4*)(&sx[r][kq << 2]) = v;
    }
    __syncthreads();

    int tx = tid & 7, ty = tid >> 3;
    int c0 = tx * 4, r0 = ty * 4;
    float acc[4][4] = {};
    for (int k = 0; k < kb; k += 4) {
        float a[4][4], b[4][4];
        #pragma unroll
        for (int rr = 0; rr < 4; ++rr)
            *(float4*)&a[rr][0] = *(const float4*)&sx[r0 + rr][k];
        #pragma unroll
        for (int j = 0; j < 4; ++j)
            *(float4*)&b[j][0] = *(const float4*)&sW[k + j][c0];
        #pragma unroll
        for (int j = 0; j < 4; ++j)
            #pragma unroll
            for (int rr = 0; rr < 4; ++rr)
                #pragma unroll
                for (int cc = 0; cc < 4; ++cc)
                    acc[rr][cc] += a[rr][j] * b[j][cc];
    }

    #pragma unroll
    for (int rr = 0; rr < 4; ++rr) {
        int gr = row0 + r0 + rr;
        if (gr < N) {
            float s = dinv[gr];
            ushort4 o;
            o.x = f2b(acc[rr][0] * s); o.y = f2b(acc[rr][1] * s);
            o.z = f2b(acc[rr][2] * s); o.w = f2b(acc[rr][3] * s);
            *(ushort4*)&xws2b[gr * F2 + c0] = o;
        }
    }
}

// ---------------- gather2: 32 cols; wave halves process alternate edges --------------
__global__ __launch_bounds__(256) void gather2(const int* __restrict__ csr,
                                               const int* __restrict__ rowptr,
                                               const int* __restrict__ deg,
                                               const float* __restrict__ dinv,
                                               const unsigned short* __restrict__ xb,
                                               const float* __restrict__ b2,
                                               float* __restrict__ h2, int N) {
    int wid = (blockIdx.x * 256 + threadIdx.x) >> 6;
    int lane = threadIdx.x & 63;
    if (wid >= N) return;
    int node = rfl(wid);
    int start = rfl(rowptr[node]);
    int cnt = rfl(deg[node]);
    int c = lane & 31, half = lane >> 5;
    float a0 = 0.f, a1 = 0.f, a2 = 0.f, a3 = 0.f;
    int j = 0;
    for (; j + 8 <= cnt; j += 8) {
        int s0 = rfl(csr[start + j]);
        int s1 = rfl(csr[start + j + 1]);
        int s2 = rfl(csr[start + j + 2]);
        int s3 = rfl(csr[start + j + 3]);
        int s4 = rfl(csr[start + j + 4]);
        int s5 = rfl(csr[start + j + 5]);
        int s6 = rfl(csr[start + j + 6]);
        int s7 = rfl(csr[start + j + 7]);
        int sa = half ? s1 : s0;
        int sb = half ? s3 : s2;
        int sc = half ? s5 : s4;
        int sd = half ? s7 : s6;
        a0 += b2f(xb[sa * F2 + c]);
        a1 += b2f(xb[sb * F2 + c]);
        a2 += b2f(xb[sc * F2 + c]);
        a3 += b2f(xb[sd * F2 + c]);
    }
    for (; j + 4 <= cnt; j += 4) {
        int s0 = rfl(csr[start + j]);
        int s1 = rfl(csr[start + j + 1]);
        int s2 = rfl(csr[start + j + 2]);
        int s3 = rfl(csr[start + j + 3]);
        int sa = half ? s1 : s0;
        int sb = half ? s3 : s2;
        a0 += b2f(xb[sa * F2 + c]);
        a1 += b2f(xb[sb * F2 + c]);
    }
    for (; j + 2 <= cnt; j += 2) {
        int s0 = rfl(csr[start + j]);
        int s1 = rfl(csr[start + j + 1]);
        int sa = half ? s1 : s0;
        a0 += b2f(xb[sa * F2 + c]);
    }
    if (j < cnt) {
        int s = rfl(csr[start + j]);
        if (half == 0) a0 += b2f(xb[s * F2 + c]);
    }
    float acc = (a0 + a1) + (a2 + a3);
    acc += __shfl_down(acc, 32, 64);
    if (half == 0) {
        float dd = dinv[node];
        float v = dd * (acc + b2f(xb[node * F2 + c])) + b2[c];
        h2[(size_t)node * F2 + c] = fmaxf(v, 0.f);
    }
}

// ---------------- GEMM3: out = h2 @ Wl + bl   [N,32]x[32,128] ----------------
__global__ __launch_bounds__(256) void gemm3(const float* __restrict__ h2,
                                             const float* __restrict__ Wl,
                                             const float* __restrict__ bl,
                                             float* __restrict__ out, int N, int kb) {
    __shared__ float sx[64][36];
    __shared__ float sW[32][128];
    int tid = threadIdx.x;
    int row0 = blockIdx.x * 64;

    for (int i = tid; i < 1024; i += 256) ((float4*)&sW[0][0])[i] = ((const float4*)Wl)[i];
    for (int i = tid; i < 512; i += 256) {
        int r = i >> 3, kq = i & 7;
        int gr = row0 + r;
        float4 v = make_float4(0.f, 0.f, 0.f, 0.f);
        if (gr < N) v = ((const float4*)(h2 + (size_t)gr * F2))[kq];
        *(float4*)(&sx[r][kq << 2]) = v;
    }
    __syncthreads();

    int tx = tid & 15, ty = tid >> 4;
    int c0 = tx * 8, r0 = ty * 4;
    float acc[4][8] = {};
    for (int k = 0; k < kb; k += 4) {
        float a[4][4], b[4][8];
        #pragma unroll
        for (int rr = 0; rr < 4; ++rr)
            *(float4*)&a[rr][0] = *(const float4*)&sx[r0 + rr][k];
        #pragma unroll
        for (int j = 0; j < 4; ++j) {
            *(float4*)&b[j][0] = *(const float4*)&sW[k + j][c0];
            *(float4*)&b[j][4] = *(const float4*)&sW[k + j][c0 + 4];
        }
        #pragma unroll
        for (int j = 0; j < 4; ++j)
            #pragma unroll
            for (int rr = 0; rr < 4; ++rr)
                #pragma unroll
                for (int cc = 0; cc < 8; ++cc)
                    acc[rr][cc] += a[rr][j] * b[j][cc];
    }

    float4 bia0 = *(const float4*)&bl[c0];
    float4 bia1 = *(const float4*)&bl[c0 + 4];
    #pragma unroll
    for (int rr = 0; rr < 4; ++rr) {
        int gr = row0 + r0 + rr;
        if (gr < N) {
            float4 o0 = make_float4(acc[rr][0] + bia0.x, acc[rr][1] + bia0.y,
                                    acc[rr][2] + bia0.z, acc[rr][3] + bia0.w);
            float4 o1 = make_float4(acc[rr][4] + bia1.x, acc[rr][5] + bia1.y,
                                    acc[rr][6] + bia1.z, acc[rr][7] + bia1.w);
            *(float4*)&out[(size_t)gr * F0 + c0] = o0;
            *(float4*)&out[(size_t)gr * F0 + c0 + 4] = o1;
        }
    }
}

extern "C" void kernel_launch(void* const* d_in, const int* in_sizes, int n_in,
                              void* d_out, int out_size, void* d_ws, size_t ws_size,
                              hipStream_t stream) {
    const float* x  = (const float*)d_in[0];
    const int*   ei = (const int*)d_in[1];
    const float* W1 = (const float*)d_in[2];
    const float* b1 = (const float*)d_in[3];
    const float* W2 = (const float*)d_in[4];
    const float* b2 = (const float*)d_in[5];
    const float* Wl = (const float*)d_in[6];
    const float* bl = (const float*)d_in[7];
    float* out = (float*)d_out;

    const int N = in_sizes[0] / F0;   // 50000
    const int E = in_sizes[1] / 2;    // 800000
    const int* src = ei;
    const int* dst = ei + E;

    char* ws = (char*)d_ws;
    size_t off = 0;
    auto alloc = [&](size_t bytes) {
        void* p = ws + off;
        off += (bytes + 255) & ~(size_t)255;
        return p;
    };
    int*            deg    = (int*)alloc((size_t)N * 4);
    float*          dinv   = (float*)alloc((size_t)N * 4);
    int*            rowptr = (int*)alloc((size_t)N * 4);
    int*            cursor = (int*)alloc((size_t)N * 4);
    int*            csr    = (int*)alloc((size_t)E * 4);
    unsigned short* xws1b  = (unsigned short*)alloc((size_t)N * F1 * 2);
    float*          h1     = (float*)alloc((size_t)N * F1 * 4);
    unsigned short* xws2b  = xws1b;   // dead after gather1
    float*          h2     = h1;      // dead after gemm2

    hipMemsetAsync(deg, 0, (size_t)N * 4, stream);
    deg_count<<<(E + 255) / 256, 256, 0, stream>>>(dst, deg, E);
    scan_all<<<1, 1024, 0, stream>>>(deg, dinv, rowptr, cursor, N);
    bucket8<<<1024, 256, 0, stream>>>(src, dst, cursor, csr, E, N);

    gemm1<<<(N + 63) / 64, 256, 0, stream>>>(x, W1, dinv, xws1b, N, 64);
    gather1<<<(N + 3) / 4, 256, 0, stream>>>(csr, rowptr, deg, dinv, xws1b, b1, h1, N);

    gemm2<<<(N + 127) / 128, 256, 0, stream>>>(h1, W2, dinv, xws2b, N, 64);
    gather2<<<(N + 3) / 4, 256, 0, stream>>>(csr, rowptr, deg, dinv, xws2b, b2, h2, N);

    gemm3<<<(N + 63) / 64, 256, 0, stream>>>(h2, Wl, bl, out, N, 32);
}

// Round 10
// 253.065 us; speedup vs baseline: 1.4868x; 1.4868x over previous
//
#include <hip/hip_runtime.h>

#define F0 128
#define F1 64
#define F2 32

__device__ __forceinline__ int rfl(int v) { return __builtin_amdgcn_readfirstlane(v); }

// bf16 helpers (RNE)
__device__ __forceinline__ unsigned short f2b(float f) {
    unsigned u = __float_as_uint(f);
    return (unsigned short)((u + 0x7fffu + ((u >> 16) & 1u)) >> 16);
}
__device__ __forceinline__ float b2f(unsigned short u) {
    return __uint_as_float(((unsigned)u) << 16);
}

// ---------------- degree ----------------
__global__ void deg_count(const int* __restrict__ dst, int* __restrict__ deg, int E) {
    int e = blockIdx.x * blockDim.x + threadIdx.x;
    if (e < E) atomicAdd(&deg[dst[e]], 1);
}

// ---------------- scan (3 kernels; round-9 post-mortem: single-block fused scan
// was 135 us latency-bound on one CU — multi-block version is ~5 us) ----------------
__global__ void scan1(const int* __restrict__ deg, float* __restrict__ dinv,
                      int* __restrict__ rowptr, int* __restrict__ bsum, int N) {
    __shared__ int s[256];
    int i = blockIdx.x * 256 + threadIdx.x;
    int v = (i < N) ? deg[i] : 0;
    if (i < N) dinv[i] = rsqrtf((float)(v + 1));  // +1 self-loop
    s[threadIdx.x] = v;
    __syncthreads();
    for (int off = 1; off < 256; off <<= 1) {
        int t = 0;
        if (threadIdx.x >= off) t = s[threadIdx.x - off];
        __syncthreads();
        if (threadIdx.x >= off) s[threadIdx.x] += t;
        __syncthreads();
    }
    if (i < N) rowptr[i] = s[threadIdx.x] - v;
    if (threadIdx.x == 255) bsum[blockIdx.x] = s[255];
}

__global__ void scan2(int* __restrict__ bsum, int* __restrict__ boff, int nb) {
    __shared__ int s[256];
    int v = (threadIdx.x < nb) ? bsum[threadIdx.x] : 0;
    s[threadIdx.x] = v;
    __syncthreads();
    for (int off = 1; off < 256; off <<= 1) {
        int t = 0;
        if (threadIdx.x >= off) t = s[threadIdx.x - off];
        __syncthreads();
        if (threadIdx.x >= off) s[threadIdx.x] += t;
        __syncthreads();
    }
    if (threadIdx.x < nb) boff[threadIdx.x] = s[threadIdx.x] - v;
}

// scan3 also copies the finalized rowptr into cursor
__global__ void scan3(int* __restrict__ rowptr, const int* __restrict__ boff,
                      int* __restrict__ cursor, int N) {
    int i = blockIdx.x * 256 + threadIdx.x;
    if (i < N) {
        int v = rowptr[i] + boff[blockIdx.x];
        rowptr[i] = v;
        cursor[i] = v;
    }
}

// ---------------- bucket, XCD-pinned by dst partition (blockIdx&7) ----------------
__global__ __launch_bounds__(256) void bucket8(const int* __restrict__ src,
                                               const int* __restrict__ dst,
                                               int* __restrict__ cursor,
                                               int* __restrict__ csr, int E, int N) {
    int part = blockIdx.x & 7;
    int g = blockIdx.x >> 3;
    int G = gridDim.x >> 3;
    int plo = (int)(((long long)N * part) >> 3);
    int phi = (int)(((long long)N * (part + 1)) >> 3);
    for (int e = g * 256 + threadIdx.x; e < E; e += G * 256) {
        int d = dst[e];
        if (d >= plo && d < phi) {
            int pos = atomicAdd(&cursor[d], 1);
            csr[pos] = src[e];
        }
    }
}

// ---------------- GEMM1: xws1b = bf16((x @ W1) * dinv[row])   [N,128]x[128,64] -------
// k-loop bound `kb` is a RUNTIME arg so the compiler cannot fully unroll
// (round-5 post-mortem: full unroll -> 256 VGPR -> 750 MB scratch spill).
__global__ __launch_bounds__(256) void gemm1(const float* __restrict__ x,
                                             const float* __restrict__ W1,
                                             const float* __restrict__ dinv,
                                             unsigned short* __restrict__ xws1b,
                                             int N, int kb) {
    __shared__ float sx[64][132];
    __shared__ float sW[64][64];
    int tid = threadIdx.x;
    int row0 = blockIdx.x * 64;

    for (int i = tid; i < 2048; i += 256) {
        int r = i >> 5, kq = i & 31;
        int gr = row0 + r;
        float4 v = make_float4(0.f, 0.f, 0.f, 0.f);
        if (gr < N) v = ((const float4*)(x + (size_t)gr * F0))[kq];
        *(float4*)(&sx[r][kq << 2]) = v;
    }

    int tx = tid & 15, ty = tid >> 4;
    int c0 = tx * 4, r0 = ty * 4;
    float acc[4][4] = {};

    const float4* W4 = (const float4*)W1;
    float4* sW4 = (float4*)(&sW[0][0]);

    for (int p = 0; p < 2; ++p) {
        if (p) __syncthreads();
        for (int i = tid; i < 1024; i += 256) sW4[i] = W4[p * 1024 + i];
        __syncthreads();
        int kbase = p * 64;
        for (int k = 0; k < kb; k += 4) {
            float a[4][4], b[4][4];
            #pragma unroll
            for (int rr = 0; rr < 4; ++rr)
                *(float4*)&a[rr][0] = *(const float4*)&sx[r0 + rr][kbase + k];
            #pragma unroll
            for (int j = 0; j < 4; ++j)
                *(float4*)&b[j][0] = *(const float4*)&sW[k + j][c0];
            #pragma unroll
            for (int j = 0; j < 4; ++j)
                #pragma unroll
                for (int rr = 0; rr < 4; ++rr)
                    #pragma unroll
                    for (int cc = 0; cc < 4; ++cc)
                        acc[rr][cc] += a[rr][j] * b[j][cc];
        }
    }

    #pragma unroll
    for (int rr = 0; rr < 4; ++rr) {
        int gr = row0 + r0 + rr;
        if (gr < N) {
            float s = dinv[gr];
            ushort4 o;
            o.x = f2b(acc[rr][0] * s); o.y = f2b(acc[rr][1] * s);
            o.z = f2b(acc[rr][2] * s); o.w = f2b(acc[rr][3] * s);
            *(ushort4*)&xws1b[gr * F1 + c0] = o;
        }
    }
}

// ---------------- gather1: h1 = relu(dinv[d]*(sum_in xws1[s] + xws1[d]) + b1) --------
__global__ __launch_bounds__(256) void gather1(const int* __restrict__ csr,
                                               const int* __restrict__ rowptr,
                                               const int* __restrict__ deg,
                                               const float* __restrict__ dinv,
                                               const unsigned short* __restrict__ xb,
                                               const float* __restrict__ b1,
                                               float* __restrict__ h1, int N) {
    int wid = (blockIdx.x * 256 + threadIdx.x) >> 6;
    int lane = threadIdx.x & 63;
    if (wid >= N) return;
    int node = rfl(wid);
    int start = rfl(rowptr[node]);
    int cnt = rfl(deg[node]);
    float a0 = 0.f, a1 = 0.f, a2 = 0.f, a3 = 0.f;
    float a4 = 0.f, a5 = 0.f, a6 = 0.f, a7 = 0.f;
    int j = 0;
    for (; j + 8 <= cnt; j += 8) {
        int s0 = rfl(csr[start + j]);
        int s1 = rfl(csr[start + j + 1]);
        int s2 = rfl(csr[start + j + 2]);
        int s3 = rfl(csr[start + j + 3]);
        int s4 = rfl(csr[start + j + 4]);
        int s5 = rfl(csr[start + j + 5]);
        int s6 = rfl(csr[start + j + 6]);
        int s7 = rfl(csr[start + j + 7]);
        a0 += b2f(xb[s0 * F1 + lane]);
        a1 += b2f(xb[s1 * F1 + lane]);
        a2 += b2f(xb[s2 * F1 + lane]);
        a3 += b2f(xb[s3 * F1 + lane]);
        a4 += b2f(xb[s4 * F1 + lane]);
        a5 += b2f(xb[s5 * F1 + lane]);
        a6 += b2f(xb[s6 * F1 + lane]);
        a7 += b2f(xb[s7 * F1 + lane]);
    }
    for (; j + 4 <= cnt; j += 4) {
        int s0 = rfl(csr[start + j]);
        int s1 = rfl(csr[start + j + 1]);
        int s2 = rfl(csr[start + j + 2]);
        int s3 = rfl(csr[start + j + 3]);
        a0 += b2f(xb[s0 * F1 + lane]);
        a1 += b2f(xb[s1 * F1 + lane]);
        a2 += b2f(xb[s2 * F1 + lane]);
        a3 += b2f(xb[s3 * F1 + lane]);
    }
    for (; j < cnt; ++j) {
        int s = rfl(csr[start + j]);
        a0 += b2f(xb[s * F1 + lane]);
    }
    float acc = ((a0 + a1) + (a2 + a3)) + ((a4 + a5) + (a6 + a7));
    float dd = dinv[node];
    float v = dd * (acc + b2f(xb[node * F1 + lane])) + b1[lane];
    h1[(size_t)node * F1 + lane] = fmaxf(v, 0.f);
}

// ---------------- GEMM2: xws2b = bf16((h1 @ W2) * dinv[row])   [N,64]x[64,32] --------
__global__ __launch_bounds__(256) void gemm2(const float* __restrict__ h1,
                                             const float* __restrict__ W2,
                                             const float* __restrict__ dinv,
                                             unsigned short* __restrict__ xws2b,
                                             int N, int kb) {
    __shared__ float sx[128][68];
    __shared__ float sW[64][32];
    int tid = threadIdx.x;
    int row0 = blockIdx.x * 128;

    for (int i = tid; i < 512; i += 256) ((float4*)&sW[0][0])[i] = ((const float4*)W2)[i];
    for (int i = tid; i < 2048; i += 256) {
        int r = i >> 4, kq = i & 15;
        int gr = row0 + r;
        float4 v = make_float4(0.f, 0.f, 0.f, 0.f);
        if (gr < N) v = ((const float4*)(h1 + (size_t)gr * F1))[kq];
        *(float4*)(&sx[r][kq << 2]) = v;
    }
    __syncthreads();

    int tx = tid & 7, ty = tid >> 3;
    int c0 = tx * 4, r0 = ty * 4;
    float acc[4][4] = {};
    for (int k = 0; k < kb; k += 4) {
        float a[4][4], b[4][4];
        #pragma unroll
        for (int rr = 0; rr < 4; ++rr)
            *(float4*)&a[rr][0] = *(const float4*)&sx[r0 + rr][k];
        #pragma unroll
        for (int j = 0; j < 4; ++j)
            *(float4*)&b[j][0] = *(const float4*)&sW[k + j][c0];
        #pragma unroll
        for (int j = 0; j < 4; ++j)
            #pragma unroll
            for (int rr = 0; rr < 4; ++rr)
                #pragma unroll
                for (int cc = 0; cc < 4; ++cc)
                    acc[rr][cc] += a[rr][j] * b[j][cc];
    }

    #pragma unroll
    for (int rr = 0; rr < 4; ++rr) {
        int gr = row0 + r0 + rr;
        if (gr < N) {
            float s = dinv[gr];
            ushort4 o;
            o.x = f2b(acc[rr][0] * s); o.y = f2b(acc[rr][1] * s);
            o.z = f2b(acc[rr][2] * s); o.w = f2b(acc[rr][3] * s);
            *(ushort4*)&xws2b[gr * F2 + c0] = o;
        }
    }
}

// ---------------- gather2: 32 cols; wave halves process alternate edges --------------
__global__ __launch_bounds__(256) void gather2(const int* __restrict__ csr,
                                               const int* __restrict__ rowptr,
                                               const int* __restrict__ deg,
                                               const float* __restrict__ dinv,
                                               const unsigned short* __restrict__ xb,
                                               const float* __restrict__ b2,
                                               float* __restrict__ h2, int N) {
    int wid = (blockIdx.x * 256 + threadIdx.x) >> 6;
    int lane = threadIdx.x & 63;
    if (wid >= N) return;
    int node = rfl(wid);
    int start = rfl(rowptr[node]);
    int cnt = rfl(deg[node]);
    int c = lane & 31, half = lane >> 5;
    float a0 = 0.f, a1 = 0.f, a2 = 0.f, a3 = 0.f;
    int j = 0;
    for (; j + 8 <= cnt; j += 8) {
        int s0 = rfl(csr[start + j]);
        int s1 = rfl(csr[start + j + 1]);
        int s2 = rfl(csr[start + j + 2]);
        int s3 = rfl(csr[start + j + 3]);
        int s4 = rfl(csr[start + j + 4]);
        int s5 = rfl(csr[start + j + 5]);
        int s6 = rfl(csr[start + j + 6]);
        int s7 = rfl(csr[start + j + 7]);
        int sa = half ? s1 : s0;
        int sb = half ? s3 : s2;
        int sc = half ? s5 : s4;
        int sd = half ? s7 : s6;
        a0 += b2f(xb[sa * F2 + c]);
        a1 += b2f(xb[sb * F2 + c]);
        a2 += b2f(xb[sc * F2 + c]);
        a3 += b2f(xb[sd * F2 + c]);
    }
    for (; j + 4 <= cnt; j += 4) {
        int s0 = rfl(csr[start + j]);
        int s1 = rfl(csr[start + j + 1]);
        int s2 = rfl(csr[start + j + 2]);
        int s3 = rfl(csr[start + j + 3]);
        int sa = half ? s1 : s0;
        int sb = half ? s3 : s2;
        a0 += b2f(xb[sa * F2 + c]);
        a1 += b2f(xb[sb * F2 + c]);
    }
    for (; j + 2 <= cnt; j += 2) {
        int s0 = rfl(csr[start + j]);
        int s1 = rfl(csr[start + j + 1]);
        int sa = half ? s1 : s0;
        a0 += b2f(xb[sa * F2 + c]);
    }
    if (j < cnt) {
        int s = rfl(csr[start + j]);
        if (half == 0) a0 += b2f(xb[s * F2 + c]);
    }
    float acc = (a0 + a1) + (a2 + a3);
    acc += __shfl_down(acc, 32, 64);
    if (half == 0) {
        float dd = dinv[node];
        float v = dd * (acc + b2f(xb[node * F2 + c])) + b2[c];
        h2[(size_t)node * F2 + c] = fmaxf(v, 0.f);
    }
}

// ---------------- GEMM3: out = h2 @ Wl + bl   [N,32]x[32,128] ----------------
__global__ __launch_bounds__(256) void gemm3(const float* __restrict__ h2,
                                             const float* __restrict__ Wl,
                                             const float* __restrict__ bl,
                                             float* __restrict__ out, int N, int kb) {
    __shared__ float sx[64][36];
    __shared__ float sW[32][128];
    int tid = threadIdx.x;
    int row0 = blockIdx.x * 64;

    for (int i = tid; i < 1024; i += 256) ((float4*)&sW[0][0])[i] = ((const float4*)Wl)[i];
    for (int i = tid; i < 512; i += 256) {
        int r = i >> 3, kq = i & 7;
        int gr = row0 + r;
        float4 v = make_float4(0.f, 0.f, 0.f, 0.f);
        if (gr < N) v = ((const float4*)(h2 + (size_t)gr * F2))[kq];
        *(float4*)(&sx[r][kq << 2]) = v;
    }
    __syncthreads();

    int tx = tid & 15, ty = tid >> 4;
    int c0 = tx * 8, r0 = ty * 4;
    float acc[4][8] = {};
    for (int k = 0; k < kb; k += 4) {
        float a[4][4], b[4][8];
        #pragma unroll
        for (int rr = 0; rr < 4; ++rr)
            *(float4*)&a[rr][0] = *(const float4*)&sx[r0 + rr][k];
        #pragma unroll
        for (int j = 0; j < 4; ++j) {
            *(float4*)&b[j][0] = *(const float4*)&sW[k + j][c0];
            *(float4*)&b[j][4] = *(const float4*)&sW[k + j][c0 + 4];
        }
        #pragma unroll
        for (int j = 0; j < 4; ++j)
            #pragma unroll
            for (int rr = 0; rr < 4; ++rr)
                #pragma unroll
                for (int cc = 0; cc < 8; ++cc)
                    acc[rr][cc] += a[rr][j] * b[j][cc];
    }

    float4 bia0 = *(const float4*)&bl[c0];
    float4 bia1 = *(const float4*)&bl[c0 + 4];
    #pragma unroll
    for (int rr = 0; rr < 4; ++rr) {
        int gr = row0 + r0 + rr;
        if (gr < N) {
            float4 o0 = make_float4(acc[rr][0] + bia0.x, acc[rr][1] + bia0.y,
                                    acc[rr][2] + bia0.z, acc[rr][3] + bia0.w);
            float4 o1 = make_float4(acc[rr][4] + bia1.x, acc[rr][5] + bia1.y,
                                    acc[rr][6] + bia1.z, acc[rr][7] + bia1.w);
            *(float4*)&out[(size_t)gr * F0 + c0] = o0;
            *(float4*)&out[(size_t)gr * F0 + c0 + 4] = o1;
        }
    }
}

extern "C" void kernel_launch(void* const* d_in, const int* in_sizes, int n_in,
                              void* d_out, int out_size, void* d_ws, size_t ws_size,
                              hipStream_t stream) {
    const float* x  = (const float*)d_in[0];
    const int*   ei = (const int*)d_in[1];
    const float* W1 = (const float*)d_in[2];
    const float* b1 = (const float*)d_in[3];
    const float* W2 = (const float*)d_in[4];
    const float* b2 = (const float*)d_in[5];
    const float* Wl = (const float*)d_in[6];
    const float* bl = (const float*)d_in[7];
    float* out = (float*)d_out;

    const int N = in_sizes[0] / F0;   // 50000
    const int E = in_sizes[1] / 2;    // 800000
    const int* src = ei;
    const int* dst = ei + E;
    const int NB = (N + 255) / 256;   // 196

    char* ws = (char*)d_ws;
    size_t off = 0;
    auto alloc = [&](size_t bytes) {
        void* p = ws + off;
        off += (bytes + 255) & ~(size_t)255;
        return p;
    };
    int*            deg    = (int*)alloc((size_t)N * 4);
    float*          dinv   = (float*)alloc((size_t)N * 4);
    int*            rowptr = (int*)alloc((size_t)N * 4);
    int*            cursor = (int*)alloc((size_t)N * 4);
    int*            bsum   = (int*)alloc((size_t)NB * 4);
    int*            boff   = (int*)alloc((size_t)NB * 4);
    int*            csr    = (int*)alloc((size_t)E * 4);
    unsigned short* xws1b  = (unsigned short*)alloc((size_t)N * F1 * 2);
    float*          h1     = (float*)alloc((size_t)N * F1 * 4);
    unsigned short* xws2b  = xws1b;   // dead after gather1
    float*          h2     = h1;      // dead after gemm2

    hipMemsetAsync(deg, 0, (size_t)N * 4, stream);
    deg_count<<<(E + 255) / 256, 256, 0, stream>>>(dst, deg, E);
    scan1<<<NB, 256, 0, stream>>>(deg, dinv, rowptr, bsum, N);
    scan2<<<1, 256, 0, stream>>>(bsum, boff, NB);
    scan3<<<NB, 256, 0, stream>>>(rowptr, boff, cursor, N);
    bucket8<<<1024, 256, 0, stream>>>(src, dst, cursor, csr, E, N);

    gemm1<<<(N + 63) / 64, 256, 0, stream>>>(x, W1, dinv, xws1b, N, 64);
    gather1<<<(N + 3) / 4, 256, 0, stream>>>(csr, rowptr, deg, dinv, xws1b, b1, h1, N);

    gemm2<<<(N + 127) / 128, 256, 0, stream>>>(h1, W2, dinv, xws2b, N, 64);
    gather2<<<(N + 3) / 4, 256, 0, stream>>>(csr, rowptr, deg, dinv, xws2b, b2, h2, N);

    gemm3<<<(N + 63) / 64, 256, 0, stream>>>(h2, Wl, bl, out, N, 32);
}

// Round 11
// 251.972 us; speedup vs baseline: 1.4933x; 1.0043x over previous
//
#include <hip/hip_runtime.h>

#define F0 128
#define F1 64
#define F2 32

__device__ __forceinline__ int rfl(int v) { return __builtin_amdgcn_readfirstlane(v); }

// bf16 helpers (RNE)
__device__ __forceinline__ unsigned short f2b(float f) {
    unsigned u = __float_as_uint(f);
    return (unsigned short)((u + 0x7fffu + ((u >> 16) & 1u)) >> 16);
}
__device__ __forceinline__ float b2f(unsigned short u) {
    return __uint_as_float(((unsigned)u) << 16);
}

// ---------------- degree ----------------
__global__ void deg_count(const int* __restrict__ dst, int* __restrict__ deg, int E) {
    int e = blockIdx.x * blockDim.x + threadIdx.x;
    if (e < E) atomicAdd(&deg[dst[e]], 1);
}

// ---------------- scan (3 kernels; round-9 post-mortem: single-block fused scan
// was 135 us latency-bound on one CU — multi-block version is ~5 us) ----------------
__global__ void scan1(const int* __restrict__ deg, float* __restrict__ dinv,
                      int* __restrict__ rowptr, int* __restrict__ bsum, int N) {
    __shared__ int s[256];
    int i = blockIdx.x * 256 + threadIdx.x;
    int v = (i < N) ? deg[i] : 0;
    if (i < N) dinv[i] = rsqrtf((float)(v + 1));  // +1 self-loop
    s[threadIdx.x] = v;
    __syncthreads();
    for (int off = 1; off < 256; off <<= 1) {
        int t = 0;
        if (threadIdx.x >= off) t = s[threadIdx.x - off];
        __syncthreads();
        if (threadIdx.x >= off) s[threadIdx.x] += t;
        __syncthreads();
    }
    if (i < N) rowptr[i] = s[threadIdx.x] - v;
    if (threadIdx.x == 255) bsum[blockIdx.x] = s[255];
}

__global__ void scan2(int* __restrict__ bsum, int* __restrict__ boff, int nb) {
    __shared__ int s[256];
    int v = (threadIdx.x < nb) ? bsum[threadIdx.x] : 0;
    s[threadIdx.x] = v;
    __syncthreads();
    for (int off = 1; off < 256; off <<= 1) {
        int t = 0;
        if (threadIdx.x >= off) t = s[threadIdx.x - off];
        __syncthreads();
        if (threadIdx.x >= off) s[threadIdx.x] += t;
        __syncthreads();
    }
    if (threadIdx.x < nb) boff[threadIdx.x] = s[threadIdx.x] - v;
}

__global__ void scan3(int* __restrict__ rowptr, const int* __restrict__ boff,
                      int* __restrict__ cursor, int N) {
    int i = blockIdx.x * 256 + threadIdx.x;
    if (i < N) {
        int v = rowptr[i] + boff[blockIdx.x];
        rowptr[i] = v;
        cursor[i] = v;
    }
}

// ---------------- bucket, XCD-pinned by dst partition (blockIdx&7) ----------------
__global__ __launch_bounds__(256) void bucket8(const int* __restrict__ src,
                                               const int* __restrict__ dst,
                                               int* __restrict__ cursor,
                                               int* __restrict__ csr, int E, int N) {
    int part = blockIdx.x & 7;
    int g = blockIdx.x >> 3;
    int G = gridDim.x >> 3;
    int plo = (int)(((long long)N * part) >> 3);
    int phi = (int)(((long long)N * (part + 1)) >> 3);
    for (int e = g * 256 + threadIdx.x; e < E; e += G * 256) {
        int d = dst[e];
        if (d >= plo && d < phi) {
            int pos = atomicAdd(&cursor[d], 1);
            csr[pos] = src[e];
        }
    }
}

// ---------------- GEMM1: xws1b = bf16((x @ W1) * dinv[row])   [N,128]x[128,64] -------
// k-loop bound `kb` is a RUNTIME arg so the compiler cannot fully unroll
// (round-5 post-mortem: full unroll -> 256 VGPR -> 750 MB scratch spill).
__global__ __launch_bounds__(256) void gemm1(const float* __restrict__ x,
                                             const float* __restrict__ W1,
                                             const float* __restrict__ dinv,
                                             unsigned short* __restrict__ xws1b,
                                             int N, int kb) {
    __shared__ float sx[64][132];
    __shared__ float sW[64][64];
    int tid = threadIdx.x;
    int row0 = blockIdx.x * 64;

    for (int i = tid; i < 2048; i += 256) {
        int r = i >> 5, kq = i & 31;
        int gr = row0 + r;
        float4 v = make_float4(0.f, 0.f, 0.f, 0.f);
        if (gr < N) v = ((const float4*)(x + (size_t)gr * F0))[kq];
        *(float4*)(&sx[r][kq << 2]) = v;
    }

    int tx = tid & 15, ty = tid >> 4;
    int c0 = tx * 4, r0 = ty * 4;
    float acc[4][4] = {};

    const float4* W4 = (const float4*)W1;
    float4* sW4 = (float4*)(&sW[0][0]);

    for (int p = 0; p < 2; ++p) {
        if (p) __syncthreads();
        for (int i = tid; i < 1024; i += 256) sW4[i] = W4[p * 1024 + i];
        __syncthreads();
        int kbase = p * 64;
        for (int k = 0; k < kb; k += 4) {
            float a[4][4], b[4][4];
            #pragma unroll
            for (int rr = 0; rr < 4; ++rr)
                *(float4*)&a[rr][0] = *(const float4*)&sx[r0 + rr][kbase + k];
            #pragma unroll
            for (int j = 0; j < 4; ++j)
                *(float4*)&b[j][0] = *(const float4*)&sW[k + j][c0];
            #pragma unroll
            for (int j = 0; j < 4; ++j)
                #pragma unroll
                for (int rr = 0; rr < 4; ++rr)
                    #pragma unroll
                    for (int cc = 0; cc < 4; ++cc)
                        acc[rr][cc] += a[rr][j] * b[j][cc];
        }
    }

    #pragma unroll
    for (int rr = 0; rr < 4; ++rr) {
        int gr = row0 + r0 + rr;
        if (gr < N) {
            float s = dinv[gr];
            ushort4 o;
            o.x = f2b(acc[rr][0] * s); o.y = f2b(acc[rr][1] * s);
            o.z = f2b(acc[rr][2] * s); o.w = f2b(acc[rr][3] * s);
            *(ushort4*)&xws1b[gr * F1 + c0] = o;
        }
    }
}

// ---- gather1 + gemm2 fused: h1-row stays in LDS; writes xws2b directly ----
// xws2b[node][c] = bf16( dinv[node] * sum_k h1[node][k] * W2[k][c] ),
// h1[node][k] = relu( dinv*(gather + self) + b1[k] ).
__global__ __launch_bounds__(256) void gather1f(const int* __restrict__ csr,
                                                const int* __restrict__ rowptr,
                                                const int* __restrict__ deg,
                                                const float* __restrict__ dinv,
                                                const unsigned short* __restrict__ xb,
                                                const float* __restrict__ b1,
                                                const float* __restrict__ W2,
                                                unsigned short* __restrict__ xws2b,
                                                int N, int kh) {
    __shared__ float sW2[F1][F2];    // 8 KB
    __shared__ float h1s[4][F1];     // 1 KB
    int tid = threadIdx.x;
    // stage W2 (all threads, before any early return), then barrier
    for (int i = tid; i < (F1 * F2) / 4; i += 256)
        ((float4*)&sW2[0][0])[i] = ((const float4*)W2)[i];
    __syncthreads();

    int wv = tid >> 6, lane = tid & 63;
    int node = blockIdx.x * 4 + wv;
    if (node >= N) return;
    int start = rfl(rowptr[node]);
    int cnt = rfl(deg[node]);

    float a0 = 0.f, a1 = 0.f, a2 = 0.f, a3 = 0.f;
    float a4 = 0.f, a5 = 0.f, a6 = 0.f, a7 = 0.f;
    int j = 0;
    for (; j + 8 <= cnt; j += 8) {
        int s0 = rfl(csr[start + j]);
        int s1 = rfl(csr[start + j + 1]);
        int s2 = rfl(csr[start + j + 2]);
        int s3 = rfl(csr[start + j + 3]);
        int s4 = rfl(csr[start + j + 4]);
        int s5 = rfl(csr[start + j + 5]);
        int s6 = rfl(csr[start + j + 6]);
        int s7 = rfl(csr[start + j + 7]);
        a0 += b2f(xb[s0 * F1 + lane]);
        a1 += b2f(xb[s1 * F1 + lane]);
        a2 += b2f(xb[s2 * F1 + lane]);
        a3 += b2f(xb[s3 * F1 + lane]);
        a4 += b2f(xb[s4 * F1 + lane]);
        a5 += b2f(xb[s5 * F1 + lane]);
        a6 += b2f(xb[s6 * F1 + lane]);
        a7 += b2f(xb[s7 * F1 + lane]);
    }
    for (; j + 4 <= cnt; j += 4) {
        int s0 = rfl(csr[start + j]);
        int s1 = rfl(csr[start + j + 1]);
        int s2 = rfl(csr[start + j + 2]);
        int s3 = rfl(csr[start + j + 3]);
        a0 += b2f(xb[s0 * F1 + lane]);
        a1 += b2f(xb[s1 * F1 + lane]);
        a2 += b2f(xb[s2 * F1 + lane]);
        a3 += b2f(xb[s3 * F1 + lane]);
    }
    for (; j < cnt; ++j) {
        int s = rfl(csr[start + j]);
        a0 += b2f(xb[s * F1 + lane]);
    }
    float acc = ((a0 + a1) + (a2 + a3)) + ((a4 + a5) + (a6 + a7));
    float dd = dinv[node];
    float h1v = fmaxf(dd * (acc + b2f(xb[node * F1 + lane])) + b1[lane], 0.f);

    // wave-local LDS round-trip (in-order DS pipeline; no cross-wave sharing)
    h1s[wv][lane] = h1v;

    // dot: output c = lane&31, k-half = (lane>>5)*32, runtime-bounded k loop
    int c = lane & 31, half = lane >> 5;
    int k0 = half * 32;
    float d0 = 0.f, d1 = 0.f, d2 = 0.f, d3 = 0.f;
    for (int k = 0; k < kh; k += 4) {
        d0 += h1s[wv][k0 + k]     * sW2[k0 + k][c];
        d1 += h1s[wv][k0 + k + 1] * sW2[k0 + k + 1][c];
        d2 += h1s[wv][k0 + k + 2] * sW2[k0 + k + 2][c];
        d3 += h1s[wv][k0 + k + 3] * sW2[k0 + k + 3][c];
    }
    float dot = (d0 + d1) + (d2 + d3);
    dot += __shfl_down(dot, 32, 64);
    if (half == 0) xws2b[node * F2 + c] = f2b(dot * dd);
}

// ---- gather2 + gemm3 fused: h2-row via LDS; writes `out` directly ----
// out[node][c] = sum_k h2[k]*Wl[k][c] + bl[c],
// h2[k] = relu( dinv*(gather + self) + b2[k] ).
__global__ __launch_bounds__(256) void gather2f(const int* __restrict__ csr,
                                                const int* __restrict__ rowptr,
                                                const int* __restrict__ deg,
                                                const float* __restrict__ dinv,
                                                const unsigned short* __restrict__ xb,
                                                const float* __restrict__ b2,
                                                const float* __restrict__ Wl,
                                                const float* __restrict__ bl,
                                                float* __restrict__ out, int N, int kh) {
    __shared__ float sWl[F2][F0];    // 16 KB
    __shared__ float h2s[4][F2];     // 512 B
    int tid = threadIdx.x;
    for (int i = tid; i < (F2 * F0) / 4; i += 256)
        ((float4*)&sWl[0][0])[i] = ((const float4*)Wl)[i];
    __syncthreads();

    int wv = tid >> 6, lane = tid & 63;
    int node = blockIdx.x * 4 + wv;
    if (node >= N) return;
    int start = rfl(rowptr[node]);
    int cnt = rfl(deg[node]);
    int c = lane & 31, half = lane >> 5;

    float a0 = 0.f, a1 = 0.f, a2 = 0.f, a3 = 0.f;
    int j = 0;
    for (; j + 8 <= cnt; j += 8) {
        int s0 = rfl(csr[start + j]);
        int s1 = rfl(csr[start + j + 1]);
        int s2 = rfl(csr[start + j + 2]);
        int s3 = rfl(csr[start + j + 3]);
        int s4 = rfl(csr[start + j + 4]);
        int s5 = rfl(csr[start + j + 5]);
        int s6 = rfl(csr[start + j + 6]);
        int s7 = rfl(csr[start + j + 7]);
        int sa = half ? s1 : s0;
        int sb = half ? s3 : s2;
        int sc = half ? s5 : s4;
        int sd = half ? s7 : s6;
        a0 += b2f(xb[sa * F2 + c]);
        a1 += b2f(xb[sb * F2 + c]);
        a2 += b2f(xb[sc * F2 + c]);
        a3 += b2f(xb[sd * F2 + c]);
    }
    for (; j + 4 <= cnt; j += 4) {
        int s0 = rfl(csr[start + j]);
        int s1 = rfl(csr[start + j + 1]);
        int s2 = rfl(csr[start + j + 2]);
        int s3 = rfl(csr[start + j + 3]);
        int sa = half ? s1 : s0;
        int sb = half ? s3 : s2;
        a0 += b2f(xb[sa * F2 + c]);
        a1 += b2f(xb[sb * F2 + c]);
    }
    for (; j + 2 <= cnt; j += 2) {
        int s0 = rfl(csr[start + j]);
        int s1 = rfl(csr[start + j + 1]);
        int sa = half ? s1 : s0;
        a0 += b2f(xb[sa * F2 + c]);
    }
    if (j < cnt) {
        int s = rfl(csr[start + j]);
        if (half == 0) a0 += b2f(xb[s * F2 + c]);
    }
    float acc = (a0 + a1) + (a2 + a3);
    acc += __shfl_down(acc, 32, 64);
    float dd = dinv[node];
    if (half == 0)
        h2s[wv][c] = fmaxf(dd * (acc + b2f(xb[node * F2 + c])) + b2[c], 0.f);

    // full wave computes 128 outputs: lane -> cols lane and lane+64
    float e0 = 0.f, e1 = 0.f, f0 = 0.f, f1 = 0.f;
    for (int k = 0; k < kh; k += 2) {
        float hk0 = h2s[wv][k], hk1 = h2s[wv][k + 1];
        e0 += hk0 * sWl[k][lane];
        e1 += hk1 * sWl[k + 1][lane];
        f0 += hk0 * sWl[k][lane + 64];
        f1 += hk1 * sWl[k + 1][lane + 64];
    }
    size_t ob = (size_t)node * F0;
    out[ob + lane]      = (e0 + e1) + bl[lane];
    out[ob + lane + 64] = (f0 + f1) + bl[lane + 64];
}

extern "C" void kernel_launch(void* const* d_in, const int* in_sizes, int n_in,
                              void* d_out, int out_size, void* d_ws, size_t ws_size,
                              hipStream_t stream) {
    const float* x  = (const float*)d_in[0];
    const int*   ei = (const int*)d_in[1];
    const float* W1 = (const float*)d_in[2];
    const float* b1 = (const float*)d_in[3];
    const float* W2 = (const float*)d_in[4];
    const float* b2 = (const float*)d_in[5];
    const float* Wl = (const float*)d_in[6];
    const float* bl = (const float*)d_in[7];
    float* out = (float*)d_out;

    const int N = in_sizes[0] / F0;   // 50000
    const int E = in_sizes[1] / 2;    // 800000
    const int* src = ei;
    const int* dst = ei + E;
    const int NB = (N + 255) / 256;   // 196

    char* ws = (char*)d_ws;
    size_t off = 0;
    auto alloc = [&](size_t bytes) {
        void* p = ws + off;
        off += (bytes + 255) & ~(size_t)255;
        return p;
    };
    int*            deg    = (int*)alloc((size_t)N * 4);
    float*          dinv   = (float*)alloc((size_t)N * 4);
    int*            rowptr = (int*)alloc((size_t)N * 4);
    int*            cursor = (int*)alloc((size_t)N * 4);
    int*            bsum   = (int*)alloc((size_t)NB * 4);
    int*            boff   = (int*)alloc((size_t)NB * 4);
    int*            csr    = (int*)alloc((size_t)E * 4);
    unsigned short* xws1b  = (unsigned short*)alloc((size_t)N * F1 * 2);
    unsigned short* xws2b  = (unsigned short*)alloc((size_t)N * F2 * 2);  // live with xws1b

    hipMemsetAsync(deg, 0, (size_t)N * 4, stream);
    deg_count<<<(E + 255) / 256, 256, 0, stream>>>(dst, deg, E);
    scan1<<<NB, 256, 0, stream>>>(deg, dinv, rowptr, bsum, N);
    scan2<<<1, 256, 0, stream>>>(bsum, boff, NB);
    scan3<<<NB, 256, 0, stream>>>(rowptr, boff, cursor, N);
    bucket8<<<1024, 256, 0, stream>>>(src, dst, cursor, csr, E, N);

    gemm1<<<(N + 63) / 64, 256, 0, stream>>>(x, W1, dinv, xws1b, N, 64);
    gather1f<<<(N + 3) / 4, 256, 0, stream>>>(csr, rowptr, deg, dinv, xws1b, b1, W2, xws2b, N, 32);
    gather2f<<<(N + 3) / 4, 256, 0, stream>>>(csr, rowptr, deg, dinv, xws2b, b2, Wl, bl, out, N, 32);
}